// Round 3
// baseline (779.577 us; speedup 1.0000x reference)
//
#include <hip/hip_runtime.h>

// 2-layer GCN: out = relu(gcn2(relu(gcn1(x))))
// gcn(x,W,b)[v] = dinv[v]*( g[v] + sum_{u->v} g[u] ) + b,  g[u]=dinv[u]*(xW)[u]
// dinv[v] = rsqrt(1 + indegree(v))
// CSR via 782-bucket counting sort. GEMM1 reads x fp32 directly (BN=256).
// Layer-2 GEMM fused into the 256-dim aggregation (hid lives only in LDS).

typedef short          s16x8 __attribute__((ext_vector_type(8)));
typedef float          f32x4 __attribute__((ext_vector_type(4)));
typedef unsigned short u16x4 __attribute__((ext_vector_type(4)));
typedef unsigned short u16x2 __attribute__((ext_vector_type(2)));

__device__ __forceinline__ float bf2f(unsigned short u) {
  union { unsigned int i; float f; } x; x.i = ((unsigned int)u) << 16; return x.f;
}
__device__ __forceinline__ unsigned short f2bf(float f) {
  union { float f; unsigned int i; } x; x.f = f;
  unsigned int r = x.i + 0x7FFFu + ((x.i >> 16) & 1u);
  return (unsigned short)(r >> 16);
}

// ---------------- CSR build (bucketed counting sort) ----------------

#define NBUCK_PAD 1024
#define BIN_CHUNK 8192

__global__ void k_zero1024(int* __restrict__ p) { p[threadIdx.x + blockIdx.x * 256] = 0; }

__global__ __launch_bounds__(256) void k_hist(const int* __restrict__ dst,
                                              int* __restrict__ bcnt, int E) {
  __shared__ int h[NBUCK_PAD];
  int t = threadIdx.x;
  for (int i = t; i < NBUCK_PAD; i += 256) h[i] = 0;
  __syncthreads();
  int stride = gridDim.x * 256;
  for (int e = blockIdx.x * 256 + t; e < E; e += stride) atomicAdd(&h[dst[e] >> 7], 1);
  __syncthreads();
  for (int i = t; i < NBUCK_PAD; i += 256) {
    int v = h[i];
    if (v) atomicAdd(bcnt + i, v);
  }
}

__global__ void k_bscan(const int* __restrict__ bcnt, int* __restrict__ bptr,
                        int* __restrict__ bcur, int* __restrict__ rowptr, int M, int E) {
  __shared__ int sh[NBUCK_PAD];
  int t = threadIdx.x;
  int v = bcnt[t];
  sh[t] = v; __syncthreads();
  int x = v;
  for (int off = 1; off < NBUCK_PAD; off <<= 1) {
    int y = (t >= off) ? sh[t - off] : 0;
    __syncthreads();
    x += y; sh[t] = x;
    __syncthreads();
  }
  bptr[t] = x - v;
  bcur[t] = x - v;
  if (t == NBUCK_PAD - 1) bptr[NBUCK_PAD] = x;
  if (t == 0) rowptr[M] = E;
}

__global__ __launch_bounds__(256) void k_bin(const int* __restrict__ src,
                                             const int* __restrict__ dst,
                                             int* __restrict__ bcur,
                                             unsigned int* __restrict__ binned, int E) {
  __shared__ int hist[NBUCK_PAD];
  __shared__ int base[NBUCK_PAD];
  int t = threadIdx.x;
  int e0 = blockIdx.x * BIN_CHUNK;
  int e1 = min(e0 + BIN_CHUNK, E);
  for (int i = t; i < NBUCK_PAD; i += 256) hist[i] = 0;
  __syncthreads();
  for (int e = e0 + t; e < e1; e += 256) atomicAdd(&hist[dst[e] >> 7], 1);
  __syncthreads();
  for (int i = t; i < NBUCK_PAD; i += 256) {
    int h = hist[i];
    base[i] = h ? atomicAdd(bcur + i, h) : 0;
    hist[i] = 0;
  }
  __syncthreads();
  for (int e = e0 + t; e < e1; e += 256) {
    int d = dst[e], s = src[e];
    int b = d >> 7;
    int p = base[b] + atomicAdd(&hist[b], 1);
    binned[p] = ((unsigned)(d & 127) << 17) | (unsigned)s;
  }
}

__global__ __launch_bounds__(256) void k_csr(const unsigned int* __restrict__ binned,
                                             const int* __restrict__ bptr,
                                             int* __restrict__ rowptr,
                                             float* __restrict__ dinv,
                                             int* __restrict__ col, int M) {
  __shared__ int deg[128];
  __shared__ int sc[128];
  __shared__ int cur[128];
  int b = blockIdx.x, t = threadIdx.x;
  int n0 = b << 7;
  int nn = min(128, M - n0);
  int e0 = bptr[b], e1 = bptr[b + 1];
  if (t < 128) deg[t] = 0;
  __syncthreads();
  for (int e = e0 + t; e < e1; e += 256) atomicAdd(&deg[(binned[e] >> 17) & 127], 1);
  __syncthreads();
  if (t < 128) sc[t] = deg[t];
  __syncthreads();
  for (int off = 1; off < 128; off <<= 1) {
    int y = 0;
    if (t < 128 && t >= off) y = sc[t - off];
    __syncthreads();
    if (t < 128) sc[t] += y;
    __syncthreads();
  }
  if (t < nn) {
    int excl = sc[t] - deg[t];
    rowptr[n0 + t] = e0 + excl;
    dinv[n0 + t] = rsqrtf((float)(deg[t] + 1));
    cur[t] = excl;
  }
  __syncthreads();
  for (int e = e0 + t; e < e1; e += 256) {
    unsigned v = binned[e];
    int dl = (v >> 17) & 127;
    int p = e0 + atomicAdd(&cur[dl], 1);
    col[p] = (int)(v & 0x1FFFFu);
  }
}

// ---------------- weight transpose+convert (tiny) ----------------

__global__ void k_cvt_wt(const float* __restrict__ W, unsigned short* __restrict__ Wt,
                         int K, int N) {
  int i = blockIdx.x * 256 + threadIdx.x;
  if (i < K * N) {
    int k = i / N, n = i % N;
    Wt[n * K + k] = f2bf(W[i]);
  }
}

// ---------------- GEMM1: g1 = dinv .* (x @ W1), x fp32 direct ----------------
// block: 512 thr = 8 waves (2 wm x 4 wn), tile 128 x 256, K=256, BK=32.

__device__ __forceinline__ int swz4(int row, int kc) { return kc ^ ((row & 3) << 3); }

__global__ __launch_bounds__(512) void k_gemm1(
    const float* __restrict__ X, const unsigned short* __restrict__ Bt,
    const float* __restrict__ dinv, unsigned short* __restrict__ G, int M) {
  const int K = 256;
  __shared__ short lA[128 * 32];   // 8 KB
  __shared__ short lB[256 * 32];   // 16 KB
  int tid = threadIdx.x;
  int wid = tid >> 6, lane = tid & 63;
  int wm = wid >> 2, wn = wid & 3;
  int l15 = lane & 15;
  int lkg = (lane >> 4) * 8;
  int bm = blockIdx.x * 128;

  f32x4 acc[4][4] = {};

  for (int kt = 0; kt < 8; ++kt) {
    int k0 = kt * 32;
    __syncthreads();
    // stage A: 128 rows x 32 k fp32 -> bf16; 1024 chunks of 4 floats
#pragma unroll
    for (int h = 0; h < 2; ++h) {
      int cid = tid + h * 512;
      int r = cid >> 3, c4 = (cid & 7) * 4;
      int gr = bm + r;
      float4 v = {0.f, 0.f, 0.f, 0.f};
      if (gr < M) v = *(const float4*)(X + (size_t)gr * K + k0 + c4);
      u16x4 o; o[0] = f2bf(v.x); o[1] = f2bf(v.y); o[2] = f2bf(v.z); o[3] = f2bf(v.w);
      *(u16x4*)(&lA[r * 32 + swz4(r, c4)]) = o;
    }
    // stage B: 256 n-rows x 32 k bf16; 1024 chunks of 8 bf16
#pragma unroll
    for (int h = 0; h < 2; ++h) {
      int cid = tid + h * 512;
      int n = cid >> 2, kc = (cid & 3) * 8;
      s16x8 v = *(const s16x8*)(Bt + (size_t)n * K + k0 + kc);
      *(s16x8*)(&lB[n * 32 + swz4(n, kc)]) = v;
    }
    __syncthreads();

    s16x8 af[4], bfr[4];
#pragma unroll
    for (int mi = 0; mi < 4; ++mi) {
      int r = wm * 64 + mi * 16 + l15;
      af[mi] = *(const s16x8*)(&lA[r * 32 + swz4(r, lkg)]);
    }
#pragma unroll
    for (int ni = 0; ni < 4; ++ni) {
      int c = wn * 64 + ni * 16 + l15;
      bfr[ni] = *(const s16x8*)(&lB[c * 32 + swz4(c, lkg)]);
    }
#pragma unroll
    for (int mi = 0; mi < 4; ++mi)
#pragma unroll
      for (int ni = 0; ni < 4; ++ni)
        acc[mi][ni] = __builtin_amdgcn_mfma_f32_16x16x32_bf16(af[mi], bfr[ni], acc[mi][ni], 0, 0, 0);
  }

#pragma unroll
  for (int mi = 0; mi < 4; ++mi) {
    int mrow0 = bm + wm * 64 + mi * 16 + (lane >> 4) * 4;
#pragma unroll
    for (int j = 0; j < 4; ++j) {
      int m = mrow0 + j;
      if (m < M) {
        float dv = dinv[m];
#pragma unroll
        for (int ni = 0; ni < 4; ++ni) {
          G[(size_t)m * 256 + wn * 64 + ni * 16 + l15] = f2bf(acc[mi][ni][j] * dv);
        }
      }
    }
  }
}

// ---------------- fused: agg(256) + bias + relu + GEMM2 + dinv -> g2 ----------------
// block: 256 thr = 4 waves, 128 nodes. Phase 1: gather into swizzled LDS (64 KB).
// Phase 2: [128x256] @ W2t^T -> [128x128], scale by dinv, write bf16 g2.

__global__ __launch_bounds__(256) void k_agg_gemm(
    const unsigned short* __restrict__ G, const int* __restrict__ rowptr,
    const int* __restrict__ col, const float* __restrict__ dinv,
    const float* __restrict__ bias, const unsigned short* __restrict__ W2t,
    unsigned short* __restrict__ G2, int M) {
  __shared__ short lH[128 * 256];   // 64 KB, XOR-swizzled rows
  int tid = threadIdx.x;
  int w = tid >> 6, lane = tid & 63;
  int l15 = lane & 15;
  int lkg = (lane >> 4) * 8;
  int n0 = blockIdx.x << 7;
  int c4 = lane * 4;
  float4 bb = *(const float4*)(bias + c4);

  // ---- phase 1: each wave aggregates 32 nodes ----
  for (int i = 0; i < 32; ++i) {
    int vl = w * 32 + i;
    int v = n0 + vl;
    float a0 = 0.f, a1 = 0.f, a2 = 0.f, a3 = 0.f;
    if (v < M) {
      size_t base = (size_t)v * 256 + c4;
      u16x4 s = *(const u16x4*)(G + base);
      a0 = bf2f(s[0]); a1 = bf2f(s[1]); a2 = bf2f(s[2]); a3 = bf2f(s[3]);
      int jb = rowptr[v], je = rowptr[v + 1];
      int j = jb;
      for (; j + 3 < je; j += 4) {
        int u0 = col[j], u1 = col[j + 1], u2 = col[j + 2], u3 = col[j + 3];
        u16x4 p0 = *(const u16x4*)(G + (size_t)u0 * 256 + c4);
        u16x4 p1 = *(const u16x4*)(G + (size_t)u1 * 256 + c4);
        u16x4 p2 = *(const u16x4*)(G + (size_t)u2 * 256 + c4);
        u16x4 p3 = *(const u16x4*)(G + (size_t)u3 * 256 + c4);
        a0 += bf2f(p0[0]) + bf2f(p1[0]) + bf2f(p2[0]) + bf2f(p3[0]);
        a1 += bf2f(p0[1]) + bf2f(p1[1]) + bf2f(p2[1]) + bf2f(p3[1]);
        a2 += bf2f(p0[2]) + bf2f(p1[2]) + bf2f(p2[2]) + bf2f(p3[2]);
        a3 += bf2f(p0[3]) + bf2f(p1[3]) + bf2f(p2[3]) + bf2f(p3[3]);
      }
      for (; j < je; ++j) {
        int u = col[j];
        u16x4 p = *(const u16x4*)(G + (size_t)u * 256 + c4);
        a0 += bf2f(p[0]); a1 += bf2f(p[1]); a2 += bf2f(p[2]); a3 += bf2f(p[3]);
      }
      float dv = dinv[v];
      a0 = fmaxf(fmaf(dv, a0, bb.x), 0.f);
      a1 = fmaxf(fmaf(dv, a1, bb.y), 0.f);
      a2 = fmaxf(fmaf(dv, a2, bb.z), 0.f);
      a3 = fmaxf(fmaf(dv, a3, bb.w), 0.f);
    }
    u16x4 o; o[0] = f2bf(a0); o[1] = f2bf(a1); o[2] = f2bf(a2); o[3] = f2bf(a3);
    *(u16x4*)(&lH[vl * 256 + (c4 ^ ((vl & 7) << 3))]) = o;
  }
  __syncthreads();

  // ---- phase 2: GEMM [128x256] x W2t[128][256] -> [128x128] ----
  f32x4 acc[8][2] = {};
#pragma unroll
  for (int kt = 0; kt < 8; ++kt) {
    int k0 = kt * 32;
    s16x8 bfr[2];
#pragma unroll
    for (int nf = 0; nf < 2; ++nf) {
      int n = w * 32 + nf * 16 + l15;
      bfr[nf] = *(const s16x8*)(W2t + (size_t)n * 256 + k0 + lkg);
    }
#pragma unroll
    for (int mf = 0; mf < 8; ++mf) {
      int row = mf * 16 + l15;
      s16x8 af = *(const s16x8*)(&lH[row * 256 + ((k0 + lkg) ^ ((row & 7) << 3))]);
#pragma unroll
      for (int nf = 0; nf < 2; ++nf)
        acc[mf][nf] = __builtin_amdgcn_mfma_f32_16x16x32_bf16(af, bfr[nf], acc[mf][nf], 0, 0, 0);
    }
  }

#pragma unroll
  for (int mf = 0; mf < 8; ++mf) {
    int ml0 = mf * 16 + (lane >> 4) * 4;
#pragma unroll
    for (int j = 0; j < 4; ++j) {
      int node = n0 + ml0 + j;
      if (node < M) {
        float dv = dinv[node];
#pragma unroll
        for (int nf = 0; nf < 2; ++nf)
          G2[(size_t)node * 128 + w * 32 + nf * 16 + l15] = f2bf(acc[mf][nf][j] * dv);
      }
    }
  }
}

// ---------------- layer-2 aggregation (128-dim, fp32 out) ----------------

__global__ __launch_bounds__(256) void k_agg128(
    const unsigned short* __restrict__ G, const int* __restrict__ rowptr,
    const int* __restrict__ col, const float* __restrict__ dinv,
    const float* __restrict__ bias, float* __restrict__ Out, int M) {
  int lane = threadIdx.x & 63;
  int v = (blockIdx.x << 2) + (threadIdx.x >> 6);
  if (v >= M) return;
  int c2 = lane * 2;
  size_t base = (size_t)v * 128 + c2;
  float a0, a1;
  {
    u16x2 s = *(const u16x2*)(G + base);
    a0 = bf2f(s[0]); a1 = bf2f(s[1]);
  }
  int jb = rowptr[v], je = rowptr[v + 1];
  int j = jb;
  for (; j + 3 < je; j += 4) {
    int u0 = col[j], u1 = col[j + 1], u2 = col[j + 2], u3 = col[j + 3];
    u16x2 p0 = *(const u16x2*)(G + (size_t)u0 * 128 + c2);
    u16x2 p1 = *(const u16x2*)(G + (size_t)u1 * 128 + c2);
    u16x2 p2 = *(const u16x2*)(G + (size_t)u2 * 128 + c2);
    u16x2 p3 = *(const u16x2*)(G + (size_t)u3 * 128 + c2);
    a0 += bf2f(p0[0]) + bf2f(p1[0]) + bf2f(p2[0]) + bf2f(p3[0]);
    a1 += bf2f(p0[1]) + bf2f(p1[1]) + bf2f(p2[1]) + bf2f(p3[1]);
  }
  for (; j < je; ++j) {
    int u = col[j];
    u16x2 p = *(const u16x2*)(G + (size_t)u * 128 + c2);
    a0 += bf2f(p[0]); a1 += bf2f(p[1]);
  }
  float dv = dinv[v];
  float2 r;
  r.x = fmaxf(fmaf(dv, a0, bias[c2 + 0]), 0.f);
  r.y = fmaxf(fmaf(dv, a1, bias[c2 + 1]), 0.f);
  *(float2*)(Out + base) = r;
}

// ---------------- launch ----------------

extern "C" void kernel_launch(void* const* d_in, const int* in_sizes, int n_in,
                              void* d_out, int out_size, void* d_ws, size_t ws_size,
                              hipStream_t stream) {
  const float* x  = (const float*)d_in[0];
  const float* W1 = (const float*)d_in[1];
  const float* b1 = (const float*)d_in[2];
  const float* W2 = (const float*)d_in[3];
  const float* b2 = (const float*)d_in[4];
  const int*   ei = (const int*)d_in[5];

  const int D_IN = 256, D_HID = 256, D_OUT = 128;
  const int M = in_sizes[0] / D_IN;    // 100000
  const int E = in_sizes[5] / 2;       // 3200000
  const int* src = ei;
  const int* dst = ei + E;

  char* p = (char*)d_ws;
  auto alloc = [&](size_t bytes) { void* r = (void*)p; p += (bytes + 255) & ~(size_t)255; return r; };
  float* dinv = (float*)alloc((size_t)M * 4);
  int* rowptr = (int*)alloc((size_t)(M + 1) * 4);
  int* bcnt   = (int*)alloc(NBUCK_PAD * 4);
  int* bptr   = (int*)alloc((NBUCK_PAD + 1) * 4);
  int* bcur   = (int*)alloc(NBUCK_PAD * 4);
  int* colx   = (int*)alloc((size_t)E * 4);
  unsigned short* w1t = (unsigned short*)alloc((size_t)D_HID * D_IN * 2);
  unsigned short* w2t = (unsigned short*)alloc((size_t)D_OUT * D_HID * 2);
  unsigned short* g1  = (unsigned short*)alloc((size_t)M * D_HID * 2);
  unsigned short* g2  = (unsigned short*)alloc((size_t)M * D_OUT * 2);
  unsigned int* binned = (unsigned int*)g1;   // g1 written only after k_csr consumed binned

  int nbuck = (M + 127) >> 7;                     // 782
  int nbin  = (E + BIN_CHUNK - 1) / BIN_CHUNK;    // 391

  k_zero1024<<<4, 256, 0, stream>>>(bcnt);
  k_hist <<<256, 256, 0, stream>>>(dst, bcnt, E);
  k_bscan<<<1, NBUCK_PAD, 0, stream>>>(bcnt, bptr, bcur, rowptr, M, E);
  k_bin  <<<nbin, 256, 0, stream>>>(src, dst, bcur, binned, E);
  k_csr  <<<nbuck, 256, 0, stream>>>(binned, bptr, rowptr, dinv, colx, M);

  k_cvt_wt<<<(D_IN * D_HID + 255) / 256, 256, 0, stream>>>(W1, w1t, D_IN, D_HID);
  k_cvt_wt<<<(D_HID * D_OUT + 255) / 256, 256, 0, stream>>>(W2, w2t, D_HID, D_OUT);

  k_gemm1   <<<nbuck, 512, 0, stream>>>(x, w1t, dinv, g1, M);
  k_agg_gemm<<<nbuck, 256, 0, stream>>>(g1, rowptr, colx, dinv, b1, w2t, g2, M);
  k_agg128  <<<(M + 3) / 4, 256, 0, stream>>>(g2, rowptr, colx, dinv, b2, (float*)d_out, M);
}

// Round 4
// 537.809 us; speedup vs baseline: 1.4495x; 1.4495x over previous
//
#include <hip/hip_runtime.h>

// 2-layer GCN: out = relu(gcn2(relu(gcn1(x))))
// gcn(x,W,b)[v] = dinv[v]*( g[v] + sum_{u->v} g[u] ) + b,  g[u]=dinv[u]*(xW)[u]
// CSR via 782-bucket counting sort. GEMM1 reads x fp32 directly.
// Aggregations are standalone LDS-free kernels (max occupancy), paired-row
// gather: one wave-dwordx4 = 1KB = 2 rows; halves vmem instruction count.

typedef short          s16x8 __attribute__((ext_vector_type(8)));
typedef float          f32x4 __attribute__((ext_vector_type(4)));
typedef unsigned short u16x8 __attribute__((ext_vector_type(8)));
typedef unsigned short u16x4 __attribute__((ext_vector_type(4)));

__device__ __forceinline__ float bf2f(unsigned short u) {
  union { unsigned int i; float f; } x; x.i = ((unsigned int)u) << 16; return x.f;
}
__device__ __forceinline__ unsigned short f2bf(float f) {
  union { float f; unsigned int i; } x; x.f = f;
  unsigned int r = x.i + 0x7FFFu + ((x.i >> 16) & 1u);
  return (unsigned short)(r >> 16);
}

// ---------------- CSR build (bucketed counting sort) ----------------

#define NBUCK_PAD 1024
#define BIN_CHUNK 8192

__global__ __launch_bounds__(256) void k_hist(const int* __restrict__ dst,
                                              int* __restrict__ bcnt, int E) {
  __shared__ int h[NBUCK_PAD];
  int t = threadIdx.x;
  for (int i = t; i < NBUCK_PAD; i += 256) h[i] = 0;
  __syncthreads();
  int stride = gridDim.x * 256;
  for (int e = blockIdx.x * 256 + t; e < E; e += stride) atomicAdd(&h[dst[e] >> 7], 1);
  __syncthreads();
  for (int i = t; i < NBUCK_PAD; i += 256) {
    int v = h[i];
    if (v) atomicAdd(bcnt + i, v);
  }
}

__global__ void k_bscan(const int* __restrict__ bcnt, int* __restrict__ bptr,
                        int* __restrict__ bcur, int* __restrict__ rowptr, int M, int E) {
  __shared__ int sh[NBUCK_PAD];
  int t = threadIdx.x;
  int v = bcnt[t];
  sh[t] = v; __syncthreads();
  int x = v;
  for (int off = 1; off < NBUCK_PAD; off <<= 1) {
    int y = (t >= off) ? sh[t - off] : 0;
    __syncthreads();
    x += y; sh[t] = x;
    __syncthreads();
  }
  bptr[t] = x - v;
  bcur[t] = x - v;
  if (t == NBUCK_PAD - 1) bptr[NBUCK_PAD] = x;
  if (t == 0) rowptr[M] = E;
}

__global__ __launch_bounds__(256) void k_bin(const int* __restrict__ src,
                                             const int* __restrict__ dst,
                                             int* __restrict__ bcur,
                                             unsigned int* __restrict__ binned, int E) {
  __shared__ int hist[NBUCK_PAD];
  __shared__ int base[NBUCK_PAD];
  int t = threadIdx.x;
  int e0 = blockIdx.x * BIN_CHUNK;
  int e1 = min(e0 + BIN_CHUNK, E);
  for (int i = t; i < NBUCK_PAD; i += 256) hist[i] = 0;
  __syncthreads();
  for (int e = e0 + t; e < e1; e += 256) atomicAdd(&hist[dst[e] >> 7], 1);
  __syncthreads();
  for (int i = t; i < NBUCK_PAD; i += 256) {
    int h = hist[i];
    base[i] = h ? atomicAdd(bcur + i, h) : 0;
    hist[i] = 0;
  }
  __syncthreads();
  for (int e = e0 + t; e < e1; e += 256) {
    int d = dst[e], s = src[e];
    int b = d >> 7;
    int p = base[b] + atomicAdd(&hist[b], 1);
    binned[p] = ((unsigned)(d & 127) << 17) | (unsigned)s;
  }
}

__global__ __launch_bounds__(256) void k_csr(const unsigned int* __restrict__ binned,
                                             const int* __restrict__ bptr,
                                             int* __restrict__ rowptr,
                                             float* __restrict__ dinv,
                                             int* __restrict__ col, int M) {
  __shared__ int deg[128];
  __shared__ int sc[128];
  __shared__ int cur[128];
  int b = blockIdx.x, t = threadIdx.x;
  int n0 = b << 7;
  int nn = min(128, M - n0);
  int e0 = bptr[b], e1 = bptr[b + 1];
  if (t < 128) deg[t] = 0;
  __syncthreads();
  for (int e = e0 + t; e < e1; e += 256) atomicAdd(&deg[(binned[e] >> 17) & 127], 1);
  __syncthreads();
  if (t < 128) sc[t] = deg[t];
  __syncthreads();
  for (int off = 1; off < 128; off <<= 1) {
    int y = 0;
    if (t < 128 && t >= off) y = sc[t - off];
    __syncthreads();
    if (t < 128) sc[t] += y;
    __syncthreads();
  }
  if (t < nn) {
    int excl = sc[t] - deg[t];
    rowptr[n0 + t] = e0 + excl;
    dinv[n0 + t] = rsqrtf((float)(deg[t] + 1));
    cur[t] = excl;
  }
  __syncthreads();
  for (int e = e0 + t; e < e1; e += 256) {
    unsigned v = binned[e];
    int dl = (v >> 17) & 127;
    int p = e0 + atomicAdd(&cur[dl], 1);
    col[p] = (int)(v & 0x1FFFFu);
  }
}

// ---------------- weight transpose+convert (both weights, one launch) ----------------

__global__ void k_cvt_w(const float* __restrict__ W1, const float* __restrict__ W2,
                        unsigned short* __restrict__ w1t, unsigned short* __restrict__ w2t) {
  int i = blockIdx.x * 256 + threadIdx.x;
  if (i < 256 * 256) {
    int k = i >> 8, n = i & 255;
    w1t[n * 256 + k] = f2bf(W1[i]);
  } else {
    int j = i - 256 * 256;
    if (j < 256 * 128) {
      int k = j >> 7, n = j & 127;
      w2t[n * 256 + k] = f2bf(W2[j]);
    }
  }
}

// ---------------- GEMM1: g1 = dinv .* (x @ W1), x fp32 direct ----------------
// 512 thr = 8 waves (2 wm x 4 wn), tile 128 x 256, K=256, BK=32.

__device__ __forceinline__ int swz4(int row, int kc) { return kc ^ ((row & 3) << 3); }

__global__ __launch_bounds__(512) void k_gemm1(
    const float* __restrict__ X, const unsigned short* __restrict__ Bt,
    const float* __restrict__ dinv, unsigned short* __restrict__ G, int M) {
  const int K = 256;
  __shared__ short lA[128 * 32];
  __shared__ short lB[256 * 32];
  int tid = threadIdx.x;
  int wid = tid >> 6, lane = tid & 63;
  int wm = wid >> 2, wn = wid & 3;
  int l15 = lane & 15;
  int lkg = (lane >> 4) * 8;
  int bm = blockIdx.x * 128;

  f32x4 acc[4][4] = {};

  for (int kt = 0; kt < 8; ++kt) {
    int k0 = kt * 32;
    __syncthreads();
#pragma unroll
    for (int h = 0; h < 2; ++h) {
      int cid = tid + h * 512;
      int r = cid >> 3, c4 = (cid & 7) * 4;
      int gr = bm + r;
      float4 v = {0.f, 0.f, 0.f, 0.f};
      if (gr < M) v = *(const float4*)(X + (size_t)gr * K + k0 + c4);
      u16x4 o; o[0] = f2bf(v.x); o[1] = f2bf(v.y); o[2] = f2bf(v.z); o[3] = f2bf(v.w);
      *(u16x4*)(&lA[r * 32 + swz4(r, c4)]) = o;
    }
#pragma unroll
    for (int h = 0; h < 2; ++h) {
      int cid = tid + h * 512;
      int n = cid >> 2, kc = (cid & 3) * 8;
      s16x8 v = *(const s16x8*)(Bt + (size_t)n * K + k0 + kc);
      *(s16x8*)(&lB[n * 32 + swz4(n, kc)]) = v;
    }
    __syncthreads();

    s16x8 af[4], bfr[4];
#pragma unroll
    for (int mi = 0; mi < 4; ++mi) {
      int r = wm * 64 + mi * 16 + l15;
      af[mi] = *(const s16x8*)(&lA[r * 32 + swz4(r, lkg)]);
    }
#pragma unroll
    for (int ni = 0; ni < 4; ++ni) {
      int c = wn * 64 + ni * 16 + l15;
      bfr[ni] = *(const s16x8*)(&lB[c * 32 + swz4(c, lkg)]);
    }
#pragma unroll
    for (int mi = 0; mi < 4; ++mi)
#pragma unroll
      for (int ni = 0; ni < 4; ++ni)
        acc[mi][ni] = __builtin_amdgcn_mfma_f32_16x16x32_bf16(af[mi], bfr[ni], acc[mi][ni], 0, 0, 0);
  }

#pragma unroll
  for (int mi = 0; mi < 4; ++mi) {
    int mrow0 = bm + wm * 64 + mi * 16 + (lane >> 4) * 4;
#pragma unroll
    for (int j = 0; j < 4; ++j) {
      int m = mrow0 + j;
      if (m < M) {
        float dv = dinv[m];
#pragma unroll
        for (int ni = 0; ni < 4; ++ni)
          G[(size_t)m * 256 + wn * 64 + ni * 16 + l15] = f2bf(acc[mi][ni][j] * dv);
      }
    }
  }
}

// ---------------- GEMM2: g2 = dinv .* (hid @ W2), BN=128 single pass ----------------
// 512 thr = 8 waves (2 wm x 4 wn), tile 128 x 128, K=256, BK=32.

__global__ __launch_bounds__(512) void k_gemm2(
    const unsigned short* __restrict__ A, const unsigned short* __restrict__ Bt,
    const float* __restrict__ dinv, unsigned short* __restrict__ G, int M) {
  const int K = 256;
  __shared__ short lA[128 * 32];
  __shared__ short lB[128 * 32];
  int tid = threadIdx.x;
  int wid = tid >> 6, lane = tid & 63;
  int wm = wid >> 2, wn = wid & 3;
  int l15 = lane & 15;
  int lkg = (lane >> 4) * 8;
  int bm = blockIdx.x * 128;

  f32x4 acc[4][2] = {};

  for (int kt = 0; kt < 8; ++kt) {
    int k0 = kt * 32;
    __syncthreads();
    {
      int r = tid >> 2, kc = (tid & 3) * 8;
      int gr = bm + r;
      s16x8 v = {0, 0, 0, 0, 0, 0, 0, 0};
      if (gr < M) v = *(const s16x8*)(A + (size_t)gr * K + k0 + kc);
      *(s16x8*)(&lA[r * 32 + swz4(r, kc)]) = v;
    }
    {
      int n = tid >> 2, kc = (tid & 3) * 8;
      s16x8 v = *(const s16x8*)(Bt + (size_t)n * K + k0 + kc);
      *(s16x8*)(&lB[n * 32 + swz4(n, kc)]) = v;
    }
    __syncthreads();

    s16x8 af[4], bfr[2];
#pragma unroll
    for (int mi = 0; mi < 4; ++mi) {
      int r = wm * 64 + mi * 16 + l15;
      af[mi] = *(const s16x8*)(&lA[r * 32 + swz4(r, lkg)]);
    }
#pragma unroll
    for (int ni = 0; ni < 2; ++ni) {
      int c = wn * 32 + ni * 16 + l15;
      bfr[ni] = *(const s16x8*)(&lB[c * 32 + swz4(c, lkg)]);
    }
#pragma unroll
    for (int mi = 0; mi < 4; ++mi)
#pragma unroll
      for (int ni = 0; ni < 2; ++ni)
        acc[mi][ni] = __builtin_amdgcn_mfma_f32_16x16x32_bf16(af[mi], bfr[ni], acc[mi][ni], 0, 0, 0);
  }

#pragma unroll
  for (int mi = 0; mi < 4; ++mi) {
    int mrow0 = bm + wm * 64 + mi * 16 + (lane >> 4) * 4;
#pragma unroll
    for (int j = 0; j < 4; ++j) {
      int m = mrow0 + j;
      if (m < M) {
        float dv = dinv[m];
#pragma unroll
        for (int ni = 0; ni < 2; ++ni)
          G[(size_t)m * 128 + wn * 32 + ni * 16 + l15] = f2bf(acc[mi][ni][j] * dv);
      }
    }
  }
}

// ---------------- aggregation: paired-row gather ----------------
// One wave per node. Lanes 0-31 handle even edge of each pair, 32-63 odd edge;
// each lane accumulates 8 (agg256) / 4 (agg128) features; halves combined by
// one shfl_xor(32) pass at the end.

__global__ __launch_bounds__(256) void k_agg256(
    const unsigned short* __restrict__ G, const int* __restrict__ rowptr,
    const int* __restrict__ col, const float* __restrict__ dinv,
    const float* __restrict__ bias, unsigned short* __restrict__ H, int M) {
  int lane = threadIdx.x & 63;
  int v = (blockIdx.x << 2) + (threadIdx.x >> 6);
  if (v >= M) return;
  int half = lane >> 5;
  int l32 = lane & 31;
  int c8 = l32 * 8;                 // 8 features per lane
  float a[8] = {};
  if (half == 0) {                  // self row
    u16x8 s = *(const u16x8*)(G + (size_t)v * 256 + c8);
#pragma unroll
    for (int i = 0; i < 8; ++i) a[i] += bf2f(s[i]);
  }
  int jb = rowptr[v], je = rowptr[v + 1];
  int j = jb;
  for (; j + 7 < je; j += 8) {      // 8 edges = 4 paired wave-loads
    int u0 = col[j + half];
    int u1 = col[j + 2 + half];
    int u2 = col[j + 4 + half];
    int u3 = col[j + 6 + half];
    u16x8 p0 = *(const u16x8*)(G + (size_t)u0 * 256 + c8);
    u16x8 p1 = *(const u16x8*)(G + (size_t)u1 * 256 + c8);
    u16x8 p2 = *(const u16x8*)(G + (size_t)u2 * 256 + c8);
    u16x8 p3 = *(const u16x8*)(G + (size_t)u3 * 256 + c8);
#pragma unroll
    for (int i = 0; i < 8; ++i)
      a[i] += (bf2f(p0[i]) + bf2f(p1[i])) + (bf2f(p2[i]) + bf2f(p3[i]));
  }
  for (; j + 1 < je; j += 2) {
    int u = col[j + half];
    u16x8 p = *(const u16x8*)(G + (size_t)u * 256 + c8);
#pragma unroll
    for (int i = 0; i < 8; ++i) a[i] += bf2f(p[i]);
  }
  if (j < je && half == 0) {
    int u = col[j];
    u16x8 p = *(const u16x8*)(G + (size_t)u * 256 + c8);
#pragma unroll
    for (int i = 0; i < 8; ++i) a[i] += bf2f(p[i]);
  }
#pragma unroll
  for (int i = 0; i < 8; ++i) a[i] += __shfl_xor(a[i], 32, 64);
  if (half == 0) {
    float dv = dinv[v];
    float4 b0 = *(const float4*)(bias + c8);
    float4 b1 = *(const float4*)(bias + c8 + 4);
    u16x8 o;
    o[0] = f2bf(fmaxf(fmaf(dv, a[0], b0.x), 0.f));
    o[1] = f2bf(fmaxf(fmaf(dv, a[1], b0.y), 0.f));
    o[2] = f2bf(fmaxf(fmaf(dv, a[2], b0.z), 0.f));
    o[3] = f2bf(fmaxf(fmaf(dv, a[3], b0.w), 0.f));
    o[4] = f2bf(fmaxf(fmaf(dv, a[4], b1.x), 0.f));
    o[5] = f2bf(fmaxf(fmaf(dv, a[5], b1.y), 0.f));
    o[6] = f2bf(fmaxf(fmaf(dv, a[6], b1.z), 0.f));
    o[7] = f2bf(fmaxf(fmaf(dv, a[7], b1.w), 0.f));
    *(u16x8*)(H + (size_t)v * 256 + c8) = o;
  }
}

__global__ __launch_bounds__(256) void k_agg128(
    const unsigned short* __restrict__ G, const int* __restrict__ rowptr,
    const int* __restrict__ col, const float* __restrict__ dinv,
    const float* __restrict__ bias, float* __restrict__ Out, int M) {
  int lane = threadIdx.x & 63;
  int v = (blockIdx.x << 2) + (threadIdx.x >> 6);
  if (v >= M) return;
  int half = lane >> 5;
  int l32 = lane & 31;
  int c4 = l32 * 4;                 // 4 features per lane
  float a[4] = {};
  if (half == 0) {
    u16x4 s = *(const u16x4*)(G + (size_t)v * 128 + c4);
#pragma unroll
    for (int i = 0; i < 4; ++i) a[i] += bf2f(s[i]);
  }
  int jb = rowptr[v], je = rowptr[v + 1];
  int j = jb;
  for (; j + 7 < je; j += 8) {
    int u0 = col[j + half];
    int u1 = col[j + 2 + half];
    int u2 = col[j + 4 + half];
    int u3 = col[j + 6 + half];
    u16x4 p0 = *(const u16x4*)(G + (size_t)u0 * 128 + c4);
    u16x4 p1 = *(const u16x4*)(G + (size_t)u1 * 128 + c4);
    u16x4 p2 = *(const u16x4*)(G + (size_t)u2 * 128 + c4);
    u16x4 p3 = *(const u16x4*)(G + (size_t)u3 * 128 + c4);
#pragma unroll
    for (int i = 0; i < 4; ++i)
      a[i] += (bf2f(p0[i]) + bf2f(p1[i])) + (bf2f(p2[i]) + bf2f(p3[i]));
  }
  for (; j + 1 < je; j += 2) {
    int u = col[j + half];
    u16x4 p = *(const u16x4*)(G + (size_t)u * 128 + c4);
#pragma unroll
    for (int i = 0; i < 4; ++i) a[i] += bf2f(p[i]);
  }
  if (j < je && half == 0) {
    int u = col[j];
    u16x4 p = *(const u16x4*)(G + (size_t)u * 128 + c4);
#pragma unroll
    for (int i = 0; i < 4; ++i) a[i] += bf2f(p[i]);
  }
#pragma unroll
  for (int i = 0; i < 4; ++i) a[i] += __shfl_xor(a[i], 32, 64);
  if (half == 0) {
    float dv = dinv[v];
    float4 bb = *(const float4*)(bias + c4);
    float4 r;
    r.x = fmaxf(fmaf(dv, a[0], bb.x), 0.f);
    r.y = fmaxf(fmaf(dv, a[1], bb.y), 0.f);
    r.z = fmaxf(fmaf(dv, a[2], bb.z), 0.f);
    r.w = fmaxf(fmaf(dv, a[3], bb.w), 0.f);
    *(float4*)(Out + (size_t)v * 128 + c4) = r;
  }
}

// ---------------- launch ----------------

extern "C" void kernel_launch(void* const* d_in, const int* in_sizes, int n_in,
                              void* d_out, int out_size, void* d_ws, size_t ws_size,
                              hipStream_t stream) {
  const float* x  = (const float*)d_in[0];
  const float* W1 = (const float*)d_in[1];
  const float* b1 = (const float*)d_in[2];
  const float* W2 = (const float*)d_in[3];
  const float* b2 = (const float*)d_in[4];
  const int*   ei = (const int*)d_in[5];

  const int D_IN = 256, D_HID = 256, D_OUT = 128;
  const int M = in_sizes[0] / D_IN;    // 100000
  const int E = in_sizes[5] / 2;       // 3200000
  const int* src = ei;
  const int* dst = ei + E;

  char* p = (char*)d_ws;
  auto alloc = [&](size_t bytes) { void* r = (void*)p; p += (bytes + 255) & ~(size_t)255; return r; };
  float* dinv = (float*)alloc((size_t)M * 4);
  int* rowptr = (int*)alloc((size_t)(M + 1) * 4);
  int* bcnt   = (int*)alloc(NBUCK_PAD * 4);
  int* bptr   = (int*)alloc((NBUCK_PAD + 1) * 4);
  int* bcur   = (int*)alloc(NBUCK_PAD * 4);
  int* colx   = (int*)alloc((size_t)E * 4);
  unsigned short* w1t = (unsigned short*)alloc((size_t)D_HID * D_IN * 2);
  unsigned short* w2t = (unsigned short*)alloc((size_t)D_OUT * D_HID * 2);
  unsigned short* g1  = (unsigned short*)alloc((size_t)M * D_HID * 2);
  unsigned short* hid = (unsigned short*)alloc((size_t)M * D_HID * 2);
  unsigned short* g2  = (unsigned short*)alloc((size_t)M * D_OUT * 2);
  unsigned int* binned = (unsigned int*)g1;   // g1 written only after k_csr consumed binned

  int nbuck = (M + 127) >> 7;                     // 782
  int nbin  = (E + BIN_CHUNK - 1) / BIN_CHUNK;    // 391

  hipMemsetAsync(bcnt, 0, NBUCK_PAD * 4, stream);
  k_hist <<<256, 256, 0, stream>>>(dst, bcnt, E);
  k_bscan<<<1, NBUCK_PAD, 0, stream>>>(bcnt, bptr, bcur, rowptr, M, E);
  k_bin  <<<nbin, 256, 0, stream>>>(src, dst, bcur, binned, E);
  k_csr  <<<nbuck, 256, 0, stream>>>(binned, bptr, rowptr, dinv, colx, M);

  k_cvt_w<<<(256 * 256 + 256 * 128 + 255) / 256, 256, 0, stream>>>(W1, W2, w1t, w2t);

  k_gemm1 <<<nbuck, 512, 0, stream>>>(x, w1t, dinv, g1, M);
  k_agg256<<<(M + 3) / 4, 256, 0, stream>>>(g1, rowptr, colx, dinv, b1, hid, M);
  k_gemm2 <<<nbuck, 512, 0, stream>>>(hid, w2t, dinv, g2, M);
  k_agg128<<<(M + 3) / 4, 256, 0, stream>>>(g2, rowptr, colx, dinv, b2, (float*)d_out, M);
}